// Round 8
// baseline (561.426 us; speedup 1.0000x reference)
//
#include <hip/hip_runtime.h>
#include <hip/hip_bf16.h>
#include <math.h>

#define N_NODES 40000
#define E_EDGES 160000
#define ETOT    (E_EDGES + N_NODES)   // 200000 (with self-loops)
#define B_GRAPH 1024
#define FXD     78
#define H_HEADS 10
#define HF      (H_HEADS * FXD)       // 780
#define HF_LD   800                   // padded leading dim (16B-aligned rows)
#define XK_LD   96                    // padded K for x (78 -> 96)
#define DOUT    128
#define DP      256
#define SCAN_TILES 40                 // 40 x 1024 >= 40000

typedef __hip_bfloat16 bf16;
typedef __attribute__((ext_vector_type(8))) short short8;
typedef __attribute__((ext_vector_type(4))) float f32x4;

static __device__ __forceinline__ void storev(float* p, float v) { *p = v; }
static __device__ __forceinline__ void storev(bf16* p, float v) { *p = __float2bfloat16(v); }

static __device__ __forceinline__ ushort f2b_bits(float v) {
    bf16 b = __float2bfloat16(v);
    return *reinterpret_cast<ushort*>(&b);
}
static __device__ __forceinline__ float b2f_bits(short u) {
    return __uint_as_float(((unsigned)(unsigned short)u) << 16);
}
static __device__ __forceinline__ int imin(int a, int b) { return a < b ? a : b; }

// R21: conflict-free LDS addressing for 32-ushort (64B) rows.
// data slot s (16B) of row r -> physical slot s ^ ((r>>1)&3).
static __device__ __forceinline__ int lds_off(int row, int slot) {
    return row * 32 + ((slot ^ ((row >> 1) & 3)) << 3);
}

// ---------- transpose tile body (shared tile passed from kernel) ----------
static __device__ void t_tile(const float* __restrict__ w, bf16* __restrict__ wt,
                              int K, int N, int ldk, int ktile, int ntile,
                              float (*tile)[33]) {
    const int kt = ktile * 32, nt = ntile * 32;
    const int tx = threadIdx.x & 31, ty = threadIdx.x >> 5;  // 256 thr: ty 0..7
#pragma unroll
    for (int i = 0; i < 32; i += 8) {
        int k = kt + ty + i, n = nt + tx;
        tile[ty + i][tx] = (k < K && n < N) ? w[(size_t)k * N + n] : 0.f;
    }
    __syncthreads();
#pragma unroll
    for (int i = 0; i < 32; i += 8) {
        int n = nt + ty + i, k = kt + tx;
        if (n < N && k < ldk) wt[(size_t)n * ldk + k] = __float2bfloat16(tile[tx][ty + i]);
    }
}

// ---------- mega-prep: xb convert + 5 transposes + wt_E + cnt/sB zero (R17) ----------
__global__ __launch_bounds__(256)
void k_prep(const float* __restrict__ x, const float* __restrict__ gat_w,
            const float* __restrict__ gcn_w, const float* __restrict__ fcg1_w,
            const float* __restrict__ fc1_w, const float* __restrict__ fc2_w,
            const float* __restrict__ aw_s, const float* __restrict__ aw_d,
            bf16* __restrict__ xb, bf16* __restrict__ wt_gat, bf16* __restrict__ wt_gcn,
            bf16* __restrict__ wt_fcg1, bf16* __restrict__ wt_fc1, bf16* __restrict__ wt_fc2,
            bf16* __restrict__ wt_E, int* __restrict__ cnt, float* __restrict__ sB) {
    __shared__ float tile[32][33];
    int p = blockIdx.x;
    const int NB_XB  = (N_NODES * XK_LD + 255) / 256;   // 15000
    const int TGAT   = 3 * 25;    // (96/32) x ceil(780/32)
    const int TGCN   = 25 * 25;   // (800/32) x 25
    const int TFCG   = 25 * 4;    // (800/32) x (128/32)
    const int TFC1   = 12 * 32;   // (384/32) x (1024/32)
    const int TFC2   = 32 * 16;   // (1024/32) x (512/32)
    const int NB_E   = (20 * XK_LD + 255) / 256;        // 8
    const int NB_CNT = (N_NODES + 255) / 256;           // 157

    if (p < NB_XB) {
        int i = p * 256 + threadIdx.x;
        if (i < N_NODES * XK_LD) {
            int r = i / XK_LD, k = i - r * XK_LD;
            xb[i] = __float2bfloat16((k < FXD) ? x[(size_t)r * FXD + k] : 0.f);
        }
        return;
    }
    p -= NB_XB;
    if (p < TGAT)  { t_tile(gat_w,  wt_gat,  FXD,  HF,   XK_LD, p % 3,  p / 3,  tile); return; }
    p -= TGAT;
    if (p < TGCN)  { t_tile(gcn_w,  wt_gcn,  HF,   HF,   HF_LD, p % 25, p / 25, tile); return; }
    p -= TGCN;
    if (p < TFCG)  { t_tile(fcg1_w, wt_fcg1, HF,   DOUT, HF_LD, p % 25, p / 25, tile); return; }
    p -= TFCG;
    if (p < TFC1)  { t_tile(fc1_w,  wt_fc1,  384,  1024, 384,   p % 12, p / 12, tile); return; }
    p -= TFC1;
    if (p < TFC2)  { t_tile(fc2_w,  wt_fc2,  1024, 512,  1024,  p % 32, p / 32, tile); return; }
    p -= TFC2;
    if (p < NB_E) {
        int idx = p * 256 + threadIdx.x;
        if (idx < 20 * XK_LD) {
            int row = idx / XK_LD, f = idx - row * XK_LD;
            float acc = 0.f;
            if (f < FXD) {
                int h = row % H_HEADS;
                const float* aw = (row < H_HEADS) ? aw_s : aw_d;
                const float* wp = gat_w + (size_t)f * HF + h * FXD;
                const float* ap = aw + h * FXD;
                for (int c = 0; c < FXD; c++) acc += wp[c] * ap[c];
            }
            wt_E[idx] = __float2bfloat16(acc);
        }
        return;
    }
    p -= NB_E;
    if (p < NB_CNT) {
        int i = p * 256 + threadIdx.x;
        if (i < N_NODES) cnt[i] = 0;
        return;
    }
    p -= NB_CNT;
    // sB zero (1024 floats, 4 blocks)
    int i = p * 256 + threadIdx.x;
    if (i < B_GRAPH) sB[i] = 0.f;
}

// ---------- MFMA bf16 GEMM (BM=128, BK=32): A via swizzled LDS dbuf, B direct from
// L2 (R25). B (weights) is small + reused -> L2-resident; skipping its LDS staging
// halves LDS traffic (48->24 KB per block-K-step), which R24's null barrier test
// identified as the binding pipe. B fragment cols clamped to N-1 (epilogue discards).
template <typename OutT, int BIAS, int RELU>
__global__ __launch_bounds__(256)
void mfma_mm(const ushort* __restrict__ A, int lda, const ushort* __restrict__ WT, int ldb,
             const float* __restrict__ bias, OutT* __restrict__ C, int ldc,
             int M, int K, int N) {
    const int RT = (M + 127) >> 7;
    const int CT = (N + 127) >> 7;
    const int p = blockIdx.x;
    const int r = (p & 7) + 8 * (p / (8 * CT));
    const int c = (p >> 3) % CT;
    if (r >= RT) return;
    const int m0 = r * 128;
    const int n0 = c * 128;

    __shared__ ushort As[2][128 * 32];
    const int tid = threadIdx.x;
    const int wave = tid >> 6, lane = tid & 63;
    const int quad = lane >> 4, l16 = lane & 15;
    const int wr = (wave & 1) * 64;   // wave row offset
    const int wc = (wave >> 1) * 64;  // wave col offset

    f32x4 acc[4][4];
#pragma unroll
    for (int mi = 0; mi < 4; mi++)
#pragma unroll
        for (int ni = 0; ni < 4; ni++) acc[mi][ni] = (f32x4){0.f, 0.f, 0.f, 0.f};

    const int ar = tid >> 1;          // staged row 0..127
    const int hh = tid & 1;           // half: data slots 2h, 2h+1
    const int ak = hh * 16;           // ushort offset within row (data layout)
    const int woff0 = lds_off(ar, 2 * hh);
    const int woff1 = lds_off(ar, 2 * hh + 1);

    int grow = m0 + ar; if (grow >= M) grow = M - 1;  // clamp; discarded in epilogue
    const ushort* arow = A + (size_t)grow * lda + ak;

    // B fragment pointers: per-lane, direct from global (L2-resident weights)
    const ushort* bptr[4];
#pragma unroll
    for (int ni = 0; ni < 4; ni++) {
        int bcol = n0 + wc + ni * 16 + l16;
        if (bcol >= N) bcol = N - 1;               // clamp; epilogue discards
        bptr[ni] = WT + (size_t)bcol * ldb + quad * 8;
    }

    uint4 a0 = *(const uint4*)(arow);
    uint4 a1 = *(const uint4*)(arow + 8);

    int buf = 0;
    for (int kb = 0; kb < K; kb += 32, buf ^= 1) {
        *(uint4*)&As[buf][woff0] = a0;
        *(uint4*)&As[buf][woff1] = a1;
        __syncthreads();
        if (kb + 32 < K) {  // prefetch next A tile
            a0 = *(const uint4*)(arow + kb + 32);
            a1 = *(const uint4*)(arow + kb + 40);
        }
        short8 af[4], bfr[4];
#pragma unroll
        for (int mi = 0; mi < 4; mi++)
            af[mi] = *(const short8*)&As[buf][lds_off(wr + mi * 16 + l16, quad)];
#pragma unroll
        for (int ni = 0; ni < 4; ni++)
            bfr[ni] = *(const short8*)(bptr[ni] + kb);
#pragma unroll
        for (int mi = 0; mi < 4; mi++)
#pragma unroll
            for (int ni = 0; ni < 4; ni++)
                acc[mi][ni] = __builtin_amdgcn_mfma_f32_16x16x32_bf16(
                    af[mi], bfr[ni], acc[mi][ni], 0, 0, 0);
        // no second barrier: double buffer
    }
#pragma unroll
    for (int mi = 0; mi < 4; mi++)
#pragma unroll
        for (int ni = 0; ni < 4; ni++)
#pragma unroll
            for (int rg = 0; rg < 4; rg++) {
                int row = m0 + wr + mi * 16 + quad * 4 + rg;
                int col = n0 + wc + ni * 16 + l16;
                if (row < M && col < N) {
                    float v = acc[mi][ni][rg];
                    if (BIAS) v += bias[col];
                    if (RELU) v = fmaxf(v, 0.f);
                    storev(&C[(size_t)row * ldc + col], v);
                }
            }
}

static inline int mm_grid(int M, int N) {
    int RT = (M + 127) >> 7, CT = (N + 127) >> 7;
    int RTpad = ((RT + 7) >> 3) << 3;
    return RTpad * CT;
}

// ---------- MFMA bf16 GEMM (BM=64, BK=32): A via swizzled LDS dbuf, B direct (R25) ----------
template <typename OutT, int BIAS, int RELU>
__global__ __launch_bounds__(256)
void mfma_mm64(const ushort* __restrict__ A, int lda, const ushort* __restrict__ WT, int ldb,
               const float* __restrict__ bias, OutT* __restrict__ C, int ldc,
               int M, int K, int N) {
    const int RT = (M + 63) >> 6;
    const int CT = (N + 127) >> 7;
    const int p = blockIdx.x;
    const int r = (p & 7) + 8 * (p / (8 * CT));
    const int c = (p >> 3) % CT;
    if (r >= RT) return;
    const int m0 = r * 64;
    const int n0 = c * 128;

    __shared__ ushort As[2][64 * 32];
    const int tid = threadIdx.x;
    const int wave = tid >> 6, lane = tid & 63;
    const int quad = lane >> 4, l16 = lane & 15;
    const int wc = wave * 32;

    f32x4 acc[4][2];
#pragma unroll
    for (int mi = 0; mi < 4; mi++)
#pragma unroll
        for (int ni = 0; ni < 2; ni++) acc[mi][ni] = (f32x4){0.f, 0.f, 0.f, 0.f};

    const int ar  = tid >> 2, asl = tid & 3;          // A: 1 slot/thread
    const int aak = asl * 8;
    const int aoff  = lds_off(ar, asl);

    int grow = m0 + ar; if (grow >= M) grow = M - 1;
    const ushort* arow = A + (size_t)grow * lda + aak;

    const ushort* bptr[2];
#pragma unroll
    for (int ni = 0; ni < 2; ni++) {
        int bcol = n0 + wc + ni * 16 + l16;
        if (bcol >= N) bcol = N - 1;
        bptr[ni] = WT + (size_t)bcol * ldb + quad * 8;
    }

    uint4 a0 = *(const uint4*)(arow);

    int buf = 0;
    for (int kb = 0; kb < K; kb += 32, buf ^= 1) {
        *(uint4*)&As[buf][aoff]  = a0;
        __syncthreads();
        if (kb + 32 < K) {
            a0 = *(const uint4*)(arow + kb + 32);
        }
        short8 af[4], bfr[2];
#pragma unroll
        for (int mi = 0; mi < 4; mi++)
            af[mi] = *(const short8*)&As[buf][lds_off(mi * 16 + l16, quad)];
#pragma unroll
        for (int ni = 0; ni < 2; ni++)
            bfr[ni] = *(const short8*)(bptr[ni] + kb);
#pragma unroll
        for (int mi = 0; mi < 4; mi++)
#pragma unroll
            for (int ni = 0; ni < 2; ni++)
                acc[mi][ni] = __builtin_amdgcn_mfma_f32_16x16x32_bf16(
                    af[mi], bfr[ni], acc[mi][ni], 0, 0, 0);
        // no second barrier: double buffer
    }
#pragma unroll
    for (int mi = 0; mi < 4; mi++)
#pragma unroll
        for (int ni = 0; ni < 2; ni++)
#pragma unroll
            for (int rg = 0; rg < 4; rg++) {
                int row = m0 + mi * 16 + quad * 4 + rg;
                int col = n0 + wc + ni * 16 + l16;
                if (row < M && col < N) {
                    float v = acc[mi][ni][rg];
                    if (BIAS) v += bias[col];
                    if (RELU) v = fmaxf(v, 0.f);
                    storev(&C[(size_t)row * ldc + col], v);
                }
            }
}

static inline int mm_grid64(int M, int N) {
    int RT = (M + 63) >> 6, CT = (N + 127) >> 7;
    int RTpad = ((RT + 7) >> 3) << 3;
    return RTpad * CT;
}

// ---------- protein fc ----------
__global__ void k_pv(const float* __restrict__ pvec, const float* __restrict__ w,
                     const float* __restrict__ b, float* __restrict__ pv) {
    __shared__ float sm[DP];
    int bg = blockIdx.x, t = threadIdx.x;
    sm[t] = pvec[(size_t)bg * DP + t];
    __syncthreads();
    float acc = 0.f;
    for (int k = 0; k < DP; k++) acc += sm[k] * w[(size_t)k * DP + t];
    pv[(size_t)bg * DP + t] = fmaxf(acc + b[t], 0.f);
}

// ---------- k/v projections ----------
__global__ void k_kv(const float* __restrict__ pv,
                     const float* __restrict__ kw, const float* __restrict__ kb,
                     const float* __restrict__ vw, const float* __restrict__ vb,
                     float* __restrict__ kbuf, float* __restrict__ vbuf) {
    __shared__ float sm[DP];
    int bg = blockIdx.x, t = threadIdx.x;
    sm[t] = pv[(size_t)bg * DP + t];
    __syncthreads();
    int o = t & 127;
    const float* w = (t < 128) ? kw : vw;
    const float* bb = (t < 128) ? kb : vb;
    float acc = 0.f;
    for (int k = 0; k < DP; k++) acc += sm[k] * w[(size_t)k * 128 + o];
    float v = acc + bb[o];
    if (t < 128) kbuf[(size_t)bg * 128 + o] = v;
    else         vbuf[(size_t)bg * 128 + o] = v;
}

// ---------- kq[b,k] = q_w @ k[b]; qbk[b] = q_b . k[b] ----------
__global__ void k_kq(const float* __restrict__ qw, const float* __restrict__ qb,
                     const float* __restrict__ kbuf, float* __restrict__ kq,
                     float* __restrict__ qbk) {
    __shared__ float kb[128];
    int b = blockIdx.x, t = threadIdx.x;  // 128 threads
    kb[t] = kbuf[(size_t)b * 128 + t];
    __syncthreads();
    float acc = 0.f;
    for (int o = 0; o < 128; o++) acc += qw[(size_t)t * 128 + o] * kb[o];
    kq[(size_t)b * 128 + t] = acc;
    if (t == 0) {
        float s = 0.f;
        for (int o = 0; o < 128; o++) s += qb[o] * kb[o];
        qbk[b] = s;
    }
}

// ---------- CSR build: count, hierarchical scan, scatter ----------
__global__ void k_count(const int* __restrict__ ei, int* __restrict__ cnt) {
    int e = blockIdx.x * blockDim.x + threadIdx.x;
    if (e >= ETOT) return;
    int d = (e < E_EDGES) ? ei[E_EDGES + e] : e - E_EDGES;
    atomicAdd(&cnt[d], 1);
}

__global__ void k_scan_tile(const int* __restrict__ cnt, int* __restrict__ tile_sums) {
    __shared__ int sm[256];
    int b = blockIdx.x, t = threadIdx.x;
    int idx = b * 1024 + t * 4;
    int4 v = {0, 0, 0, 0};
    if (idx + 3 < N_NODES) v = *(const int4*)(cnt + idx);
    else {
        v.x = (idx     < N_NODES) ? cnt[idx]     : 0;
        v.y = (idx + 1 < N_NODES) ? cnt[idx + 1] : 0;
        v.z = (idx + 2 < N_NODES) ? cnt[idx + 2] : 0;
        v.w = (idx + 3 < N_NODES) ? cnt[idx + 3] : 0;
    }
    sm[t] = v.x + v.y + v.z + v.w;
    __syncthreads();
    for (int off = 128; off > 0; off >>= 1) {
        if (t < off) sm[t] += sm[t + off];
        __syncthreads();
    }
    if (t == 0) tile_sums[b] = sm[0];
}

__global__ void k_scan_top(const int* __restrict__ tile_sums, int* __restrict__ tile_off,
                           int* __restrict__ rowptr) {
    if (threadIdx.x == 0) {
        int run = 0;
        for (int i = 0; i < SCAN_TILES; i++) { tile_off[i] = run; run += tile_sums[i]; }
        rowptr[N_NODES] = run;
    }
}

// R17: also emits dinv (from cnt) and gstart (from batch) -- 2 fewer launches.
__global__ void k_scan_write(const int* __restrict__ cnt, const int* __restrict__ tile_off,
                             const int* __restrict__ batch,
                             int* __restrict__ rowptr, int* __restrict__ cursor,
                             float* __restrict__ dinv, int* __restrict__ gstart) {
    __shared__ int sm[256];
    int b = blockIdx.x, t = threadIdx.x;
    int idx = b * 1024 + t * 4;
    int4 v = {0, 0, 0, 0};
    if (idx + 3 < N_NODES) v = *(const int4*)(cnt + idx);
    else {
        v.x = (idx     < N_NODES) ? cnt[idx]     : 0;
        v.y = (idx + 1 < N_NODES) ? cnt[idx + 1] : 0;
        v.z = (idx + 2 < N_NODES) ? cnt[idx + 2] : 0;
        v.w = (idx + 3 < N_NODES) ? cnt[idx + 3] : 0;
    }
    int tsum = v.x + v.y + v.z + v.w;
    sm[t] = tsum;
    __syncthreads();
    for (int off = 1; off < 256; off <<= 1) {
        int add = (t >= off) ? sm[t - off] : 0;
        __syncthreads();
        sm[t] += add;
        __syncthreads();
    }
    int toff = tile_off[b] + sm[t] - tsum;  // exclusive thread offset
    int e0 = toff, e1 = e0 + v.x, e2 = e1 + v.y, e3 = e2 + v.z;
    if (idx     < N_NODES) { rowptr[idx]     = e0; cursor[idx]     = e0; }
    if (idx + 1 < N_NODES) { rowptr[idx + 1] = e1; cursor[idx + 1] = e1; }
    if (idx + 2 < N_NODES) { rowptr[idx + 2] = e2; cursor[idx + 2] = e2; }
    if (idx + 3 < N_NODES) { rowptr[idx + 3] = e3; cursor[idx + 3] = e3; }
    int cc[4] = {v.x, v.y, v.z, v.w};
#pragma unroll
    for (int j = 0; j < 4; j++) {
        int n = idx + j;
        if (n >= N_NODES) break;
        dinv[n] = (cc[j] > 0) ? 1.0f / sqrtf((float)cc[j]) : 0.f;
        int bg = batch[n];
        int bp = (n == 0) ? -1 : batch[n - 1];
        for (int g = bp + 1; g <= bg; g++) gstart[g] = n;
        if (n == N_NODES - 1)
            for (int g = bg + 1; g <= B_GRAPH; g++) gstart[g] = N_NODES;
    }
}

// scatter resolves src directly: aggregation chain loses the ei[e] hop (R13).
__global__ void k_scatter(const int* __restrict__ ei, int* __restrict__ cursor,
                          int* __restrict__ slist) {
    int e = blockIdx.x * blockDim.x + threadIdx.x;
    if (e >= ETOT) return;
    int s, d;
    if (e < E_EDGES) { s = ei[e]; d = ei[E_EDGES + e]; }
    else             { s = d = e - E_EDGES; }
    int pos = atomicAdd(&cursor[d], 1);
    slist[pos] = s;
}

// ---------- fused GAT softmax + aggregation: wave-per-dst, depth-2 ring (R20) ----------
__global__ __launch_bounds__(256)
void k_gat_fused(const int* __restrict__ rowptr, const int* __restrict__ slist,
                 const bf16* __restrict__ h, const float* __restrict__ aa,
                 const float* __restrict__ bias, bf16* __restrict__ outb) {
    const int tid = threadIdx.x;
    const int w = tid >> 6, lane = tid & 63;
    const int d = blockIdx.x * 4 + w;
    const int beg = rowptr[d], end = rowptr[d + 1];

    const float adst_l = (lane < H_HEADS) ? aa[(size_t)d * 20 + 10 + lane] : 0.f;

    const int cA = lane * 8;
    const int cB = (lane + 64) * 8;
    const bool hasB = cB < HF_LD;  // lane < 36
    int hloA = cA / FXD;       if (hloA > 9) hloA = 9;
    int hhiA = (cA + 7) / FXD; if (hhiA > 9) hhiA = 9;
    int hloB = cB / FXD;       if (hloB > 9) hloB = 9;
    int hhiB = (cB + 7) / FXD; if (hhiB > 9) hhiB = 9;
    bool selA[8], selB[8];
#pragma unroll
    for (int j = 0; j < 8; j++) {
        int ha = (cA + j) / FXD; if (ha > 9) ha = 9;
        int hb = (cB + j) / FXD; if (hb > 9) hb = 9;
        selA[j] = (ha != hloA);
        selB[j] = (hb != hloB);
    }
    float accA[8], accB[8];
#pragma unroll
    for (int j = 0; j < 8; j++) { accA[j] = 0.f; accB[j] = 0.f; }
    float s_l = 0.f;

    const ushort* hb16 = (const ushort*)h;
    const int e1 = end - 1;   // deg >= 1 guaranteed (self-loop)

    auto edge = [&](float ae, const short8& va, const short8& vb) {
        float ex = 0.f;
        if (lane < H_HEADS) {
            float a = ae + adst_l;
            a = (a >= 0.f) ? a : 0.2f * a;
            ex = __expf(a);
            s_l += ex;
        }
        float exloA = __shfl(ex, hloA), exhiA = __shfl(ex, hhiA);
#pragma unroll
        for (int j = 0; j < 8; j++)
            accA[j] += (selA[j] ? exhiA : exloA) * b2f_bits(va[j]);
        if (hasB) {
            float exloB = __shfl(ex, hloB), exhiB = __shfl(ex, hhiB);
#pragma unroll
            for (int j = 0; j < 8; j++)
                accB[j] += (selB[j] ? exhiB : exloB) * b2f_bits(vb[j]);
        }
    };

    // ring state: rows of edges i,i+1 resident; src indices of i+2,i+3 resident
    int s0 = slist[beg];
    int s1 = slist[imin(beg + 1, e1)];
    int s2 = slist[imin(beg + 2, e1)];
    int s3 = slist[imin(beg + 3, e1)];
    short8 va0, va1, vb0 = {0,0,0,0,0,0,0,0}, vb1 = {0,0,0,0,0,0,0,0};
    float a0 = 0.f, a1 = 0.f;
    {
        const ushort* hr0 = hb16 + (size_t)s0 * HF_LD;
        const ushort* hr1 = hb16 + (size_t)s1 * HF_LD;
        va0 = *(const short8*)(hr0 + cA);
        va1 = *(const short8*)(hr1 + cA);
        if (hasB) { vb0 = *(const short8*)(hr0 + cB); vb1 = *(const short8*)(hr1 + cB); }
        if (lane < H_HEADS) {
            a0 = aa[(size_t)s0 * 20 + lane];
            a1 = aa[(size_t)s1 * 20 + lane];
        }
    }
    int i = beg;
    for (; i + 1 < end; i += 2) {
        // row loads for edges i+2,i+3: addresses already resident, issue immediately
        const ushort* hr2 = hb16 + (size_t)s2 * HF_LD;
        const ushort* hr3 = hb16 + (size_t)s3 * HF_LD;
        short8 nva0 = *(const short8*)(hr2 + cA);
        short8 nva1 = *(const short8*)(hr3 + cA);
        short8 nvb0 = vb0, nvb1 = vb1;
        if (hasB) { nvb0 = *(const short8*)(hr2 + cB); nvb1 = *(const short8*)(hr3 + cB); }
        float na0 = 0.f, na1 = 0.f;
        if (lane < H_HEADS) {
            na0 = aa[(size_t)s2 * 20 + lane];
            na1 = aa[(size_t)s3 * 20 + lane];
        }
        // index prefetch for i+4,i+5 (independent loads)
        int ns2 = slist[imin(i + 4, e1)];
        int ns3 = slist[imin(i + 5, e1)];
        // compute edges i, i+1 (order preserved)
        edge(a0, va0, vb0);
        edge(a1, va1, vb1);
        va0 = nva0; vb0 = nvb0; a0 = na0;
        va1 = nva1; vb1 = nvb1; a1 = na1;
        s2 = ns2; s3 = ns3;
    }
    if (i < end) edge(a0, va0, vb0);

    float sinv_l = 1.f / (s_l + 1e-16f);  // valid for lanes<10

    ushort* orow = (ushort*)outb + (size_t)d * HF_LD;
    {
        float silo = __shfl(sinv_l, hloA), sihi = __shfl(sinv_l, hhiA);
        union { ushort u[8]; uint4 q; } pk;
#pragma unroll
        for (int j = 0; j < 8; j++) {
            float bz = (cA + j < HF) ? bias[cA + j] : 0.f;
            pk.u[j] = f2b_bits(fmaxf(accA[j] * (selA[j] ? sihi : silo) + bz, 0.f));
        }
        *(uint4*)(orow + cA) = pk.q;
    }
    if (hasB) {
        float silo = __shfl(sinv_l, hloB), sihi = __shfl(sinv_l, hhiB);
        union { ushort u[8]; uint4 q; } pk;
#pragma unroll
        for (int j = 0; j < 8; j++) {
            float bz = (cB + j < HF) ? bias[cB + j] : 0.f;
            pk.u[j] = f2b_bits(fmaxf(accB[j] * (selB[j] ? sihi : silo) + bz, 0.f));
        }
        *(uint4*)(orow + cB) = pk.q;
    }
}

// ---------- GCN aggregation: wave-per-dst, depth-2 ring (R20) ----------
__global__ __launch_bounds__(256)
void k_gcn_aggr_v(const int* __restrict__ rowptr, const int* __restrict__ slist,
                  const bf16* __restrict__ hg,
                  const float* __restrict__ dinv, const float* __restrict__ bias,
                  bf16* __restrict__ outb) {
    const int tid = threadIdx.x;
    const int w = tid >> 6, lane = tid & 63;
    const int d = blockIdx.x * 4 + w;
    const float dv = dinv[d];
    const int cA = lane * 8;
    const int cB = (lane + 64) * 8;
    const bool hasB = cB < HF_LD;
    float accA[8], accB[8];
#pragma unroll
    for (int j = 0; j < 8; j++) { accA[j] = 0.f; accB[j] = 0.f; }
    const int beg = rowptr[d], end = rowptr[d + 1];
    const ushort* hb16 = (const ushort*)hg;
    const int e1 = end - 1;

    auto edge = [&](float we, const short8& va, const short8& vb) {
#pragma unroll
        for (int j = 0; j < 8; j++) accA[j] += we * b2f_bits(va[j]);
        if (hasB) {
#pragma unroll
            for (int j = 0; j < 8; j++) accB[j] += we * b2f_bits(vb[j]);
        }
    };

    int s0 = slist[beg];
    int s1 = slist[imin(beg + 1, e1)];
    int s2 = slist[imin(beg + 2, e1)];
    int s3 = slist[imin(beg + 3, e1)];
    short8 va0, va1, vb0 = {0,0,0,0,0,0,0,0}, vb1 = {0,0,0,0,0,0,0,0};
    float w0, w1;
    {
        const ushort* hr0 = hb16 + (size_t)s0 * HF_LD;
        const ushort* hr1 = hb16 + (size_t)s1 * HF_LD;
        va0 = *(const short8*)(hr0 + cA);
        va1 = *(const short8*)(hr1 + cA);
        if (hasB) { vb0 = *(const short8*)(hr0 + cB); vb1 = *(const short8*)(hr1 + cB); }
        w0 = dinv[s0] * dv;
        w1 = dinv[s1] * dv;
    }
    int i = beg;
    for (; i + 1 < end; i += 2) {
        const ushort* hr2 = hb16 + (size_t)s2 * HF_LD;
        const ushort* hr3 = hb16 + (size_t)s3 * HF_LD;
        short8 nva0 = *(const short8*)(hr2 + cA);
        short8 nva1 = *(const short8*)(hr3 + cA);
        short8 nvb0 = vb0, nvb1 = vb1;
        if (hasB) { nvb0 = *(const short8*)(hr2 + cB); nvb1 = *(const short8*)(hr3 + cB); }
        float nw0 = dinv[s2] * dv;
        float nw1 = dinv[s3] * dv;
        int ns2 = slist[imin(i + 4, e1)];
        int ns3 = slist[imin(i + 5, e1)];
        edge(w0, va0, vb0);
        edge(w1, va1, vb1);
        va0 = nva0; vb0 = nvb0; w0 = nw0;
        va1 = nva1; vb1 = nvb1; w1 = nw1;
        s2 = ns2; s3 = ns3;
    }
    if (i < end) edge(w0, va0, vb0);

    ushort* orow = (ushort*)outb + (size_t)d * HF_LD;
    {
        union { ushort u[8]; uint4 q; } pk;
#pragma unroll
        for (int j = 0; j < 8; j++) {
            float bz = (cA + j < HF) ? bias[cA + j] : 0.f;
            pk.u[j] = f2b_bits(fmaxf(accA[j] + bz, 0.f));
        }
        *(uint4*)(orow + cA) = pk.q;
    }
    if (hasB) {
        union { ushort u[8]; uint4 q; } pk;
#pragma unroll
        for (int j = 0; j < 8; j++) {
            float bz = (cB + j < HF) ? bias[cB + j] : 0.f;
            pk.u[j] = f2b_bits(fmaxf(accB[j] + bz, 0.f));
        }
        *(uint4*)(orow + cB) = pk.q;
    }
}

// ---------- cross-attention: exp(score) + segment sum (dn in bf16, R17) ----------
__global__ void k_scores_e(const bf16* __restrict__ dnb, const float* __restrict__ kq,
                           const float* __restrict__ qbk, const int* __restrict__ batch,
                           float* __restrict__ enode, float* __restrict__ sB) {
    int wv = (blockIdx.x * blockDim.x + threadIdx.x) >> 6;
    int lane = threadIdx.x & 63;
    if (wv >= N_NODES) return;
    int b = batch[wv];
    const ushort* dp = (const ushort*)dnb + (size_t)wv * DOUT;
    const float* kp = kq + (size_t)b * DOUT;
    uint dd = *(const uint*)(dp + lane * 2);
    float p = b2f_bits((ushort)dd) * kp[lane * 2]
            + b2f_bits((ushort)(dd >> 16)) * kp[lane * 2 + 1];
    for (int off = 32; off > 0; off >>= 1) p += __shfl_down(p, off);
    if (lane == 0) {
        float ex = __expf((p + qbk[b]) * 0.08838834764831845f);  // 1/sqrt(128)
        enode[wv] = ex;
        atomicAdd(&sB[b], ex);
    }
}

// ---------- per-graph pool + concat -> xcb (dn in bf16, uint loads, R17) ----------
__global__ __launch_bounds__(384)
void k_pool_xc(const bf16* __restrict__ dnb, const float* __restrict__ vbuf,
               const float* __restrict__ enode, const float* __restrict__ sB,
               const int* __restrict__ gstart, const float* __restrict__ pv,
               bf16* __restrict__ xcb) {
    int g = blockIdx.x, t = threadIdx.x;
    if (t < 64) {
        int s0 = gstart[g], s1 = gstart[g + 1];
        float inv = 1.f / sB[g];  // unused if empty
        float vb0 = vbuf[(size_t)g * 128 + 2 * t];
        float vb1 = vbuf[(size_t)g * 128 + 2 * t + 1];
        float m0 = -3.4e38f, m1 = -3.4e38f;
        const ushort* dp = (const ushort*)dnb;
        for (int n = s0; n < s1; n++) {
            uint dd = *(const uint*)(dp + (size_t)n * 128 + 2 * t);
            float a = enode[n] * inv;
            m0 = fmaxf(m0, b2f_bits((ushort)dd) + a * vb0);
            m1 = fmaxf(m1, b2f_bits((ushort)(dd >> 16)) + a * vb1);
        }
        bool ne = s1 > s0;
        xcb[(size_t)g * 384 + 2 * t]     = __float2bfloat16(ne ? m0 : 0.f);
        xcb[(size_t)g * 384 + 2 * t + 1] = __float2bfloat16(ne ? m1 : 0.f);
    } else if (t >= 128) {
        xcb[(size_t)g * 384 + t] = __float2bfloat16(pv[(size_t)g * DP + (t - 128)]);
    }
}

// ---------- final head ----------
__global__ void k_out(const float* __restrict__ h2, const float* __restrict__ ow,
                      const float* __restrict__ ob, float* __restrict__ out) {
    int row = (blockIdx.x * blockDim.x + threadIdx.x) >> 6;
    int lane = threadIdx.x & 63;
    if (row >= B_GRAPH) return;
    float p = 0.f;
    for (int j = lane; j < 512; j += 64) p += h2[(size_t)row * 512 + j] * ow[j];
    for (int off = 32; off > 0; off >>= 1) p += __shfl_down(p, off);
    if (lane == 0) out[row] = p + ob[0];
}

// ---------- workspace-overflow sentinel ----------
__global__ void k_fail(float* __restrict__ out, int n) {
    int i = blockIdx.x * blockDim.x + threadIdx.x;
    if (i < n) out[i] = 12345.0f;
}

extern "C" void kernel_launch(void* const* d_in, const int* in_sizes, int n_in,
                              void* d_out, int out_size, void* d_ws, size_t ws_size,
                              hipStream_t stream) {
    const float* x        = (const float*)d_in[0];
    const int*   ei       = (const int*)d_in[1];
    const int*   batch    = (const int*)d_in[2];
    const float* pvec     = (const float*)d_in[3];
    const float* pfc_w    = (const float*)d_in[4];
    const float* pfc_b    = (const float*)d_in[5];
    const float* gat_w    = (const float*)d_in[6];
    const float* gat_asrc = (const float*)d_in[7];
    const float* gat_adst = (const float*)d_in[8];
    const float* gat_b    = (const float*)d_in[9];
    const float* gcn_w    = (const float*)d_in[10];
    const float* gcn_b    = (const float*)d_in[11];
    const float* fcg1_w   = (const float*)d_in[12];
    const float* fcg1_b   = (const float*)d_in[13];
    const float* q_w      = (const float*)d_in[14];
    const float* q_b      = (const float*)d_in[15];
    const float* k_w      = (const float*)d_in[16];
    const float* k_b      = (const float*)d_in[17];
    const float* v_w      = (const float*)d_in[18];
    const float* v_b      = (const float*)d_in[19];
    const float* fc1_w    = (const float*)d_in[20];
    const float* fc1_b    = (const float*)d_in[21];
    const float* fc2_w    = (const float*)d_in[22];
    const float* fc2_b    = (const float*)d_in[23];
    const float* out_w    = (const float*)d_in[24];
    const float* out_b    = (const float*)d_in[25];
    float* out = (float*)d_out;

    // ---- workspace layout (bytes, 256-aligned) ----
    char* base = (char*)d_ws;
    size_t off = 0;
    auto alloc = [&](size_t bytes) -> void* {
        void* r = base + off;
        off += (bytes + 255) & ~(size_t)255;
        return r;
    };
    float*    pv      = (float*)alloc((size_t)B_GRAPH * DP * 4);
    bf16*     xb      = (bf16*)alloc((size_t)N_NODES * XK_LD * 2);
    bf16*     wt_gat  = (bf16*)alloc((size_t)HF * XK_LD * 2);
    bf16*     wt_gcn  = (bf16*)alloc((size_t)HF * HF_LD * 2);
    bf16*     wt_fcg1 = (bf16*)alloc((size_t)DOUT * HF_LD * 2);
    bf16*     wt_fc1  = (bf16*)alloc((size_t)1024 * 384 * 2);
    bf16*     wt_fc2  = (bf16*)alloc((size_t)512 * 1024 * 2);
    bf16*     wt_E    = (bf16*)alloc((size_t)20 * XK_LD * 2);
    bf16*     hB      = (bf16*)alloc((size_t)N_NODES * HF_LD * 2);  // h, then hg (ld 800)
    bf16*     g1      = (bf16*)alloc((size_t)N_NODES * HF_LD * 2);  // aggr outs (ld 800)
    float*    aa      = (float*)alloc((size_t)N_NODES * 20 * 4);    // [n][20] logits
    int*      cnt     = (int*)alloc((size_t)N_NODES * 4);
    int*      rowptr  = (int*)alloc((size_t)(N_NODES + 1) * 4);
    int*      cursor  = (int*)alloc((size_t)N_NODES * 4);
    int*      slist   = (int*)alloc((size_t)ETOT * 4);
    int*      tsums   = (int*)alloc((size_t)SCAN_TILES * 4);
    int*      toff    = (int*)alloc((size_t)SCAN_TILES * 4);
    int*      gstart  = (int*)alloc((size_t)(B_GRAPH + 1) * 4);
    float*    dinv    = (float*)alloc((size_t)N_NODES * 4);
    bf16*     dnb     = (bf16*)alloc((size_t)N_NODES * DOUT * 2);
    float*    kbuf    = (float*)alloc((size_t)B_GRAPH * 128 * 4);
    float*    vbuf    = (float*)alloc((size_t)B_GRAPH * 128 * 4);
    float*    kq      = (float*)alloc((size_t)B_GRAPH * 128 * 4);
    float*    qbk     = (float*)alloc((size_t)B_GRAPH * 4);
    float*    enode   = (float*)alloc((size_t)N_NODES * 4);
    float*    sB      = (float*)alloc((size_t)B_GRAPH * 4);
    bf16*     xcb     = (bf16*)alloc((size_t)B_GRAPH * 384 * 2);
    bf16*     h1b     = (bf16*)alloc((size_t)B_GRAPH * 1024 * 2);
    float*    h2      = (float*)alloc((size_t)B_GRAPH * 512 * 4);

    if (off > ws_size) {
        k_fail<<<(out_size + 255) / 256, 256, 0, stream>>>(out, out_size);
        return;
    }

    // ---- mega-prep (converts + transposes + wt_E + cnt/sB zero) ----
    {
        int nb = (N_NODES * XK_LD + 255) / 256   // xb
               + 3 * 25 + 25 * 25 + 25 * 4 + 12 * 32 + 32 * 16  // transposes
               + (20 * XK_LD + 255) / 256        // wt_E
               + (N_NODES + 255) / 256           // cnt zero
               + (B_GRAPH + 255) / 256;          // sB zero
        k_prep<<<nb, 256, 0, stream>>>(x, gat_w, gcn_w, fcg1_w, fc1_w, fc2_w,
                                       gat_asrc, gat_adst,
                                       xb, wt_gat, wt_gcn, wt_fcg1, wt_fc1, wt_fc2,
                                       wt_E, cnt, sB);
    }

    // ---- protein path ----
    k_pv<<<B_GRAPH, 256, 0, stream>>>(pvec, pfc_w, pfc_b, pv);
    k_kv<<<B_GRAPH, 256, 0, stream>>>(pv, k_w, k_b, v_w, v_b, kbuf, vbuf);
    k_kq<<<B_GRAPH, 128, 0, stream>>>(q_w, q_b, kbuf, kq, qbk);

    // ---- CSR build + dinv + graph ranges ----
    k_count<<<(ETOT + 255) / 256, 256, 0, stream>>>(ei, cnt);
    k_scan_tile<<<SCAN_TILES, 256, 0, stream>>>(cnt, tsums);
    k_scan_top<<<1, 64, 0, stream>>>(tsums, toff, rowptr);
    k_scan_write<<<SCAN_TILES, 256, 0, stream>>>(cnt, toff, batch, rowptr, cursor,
                                                 dinv, gstart);
    k_scatter<<<(ETOT + 255) / 256, 256, 0, stream>>>(ei, cursor, slist);

    // ---- GAT: logits GEMM + feature GEMM + fused aggr ----
    mfma_mm64<float, 0, 0><<<mm_grid64(N_NODES, 20), 256, 0, stream>>>(
        (const ushort*)xb, XK_LD, (const ushort*)wt_E, XK_LD, nullptr, aa, 20,
        N_NODES, XK_LD, 20);
    mfma_mm<bf16, 0, 0><<<mm_grid(N_NODES, HF), 256, 0, stream>>>(
        (const ushort*)xb, XK_LD, (const ushort*)wt_gat, XK_LD, nullptr, hB, HF_LD,
        N_NODES, XK_LD, HF);
    k_gat_fused<<<N_NODES / 4, 256, 0, stream>>>(rowptr, slist, hB, aa, gat_b, g1);

    // ---- GCN (B-direct GEMM, R25) ----
    mfma_mm<bf16, 0, 0><<<mm_grid(N_NODES, HF), 256, 0, stream>>>(
        (const ushort*)g1, HF_LD, (const ushort*)wt_gcn, HF_LD, nullptr, hB, HF_LD,
        N_NODES, HF_LD, HF);
    k_gcn_aggr_v<<<N_NODES / 4, 256, 0, stream>>>(rowptr, slist, hB, dinv, gcn_b, g1);

    // ---- fc_g1 (bf16 out) ----
    mfma_mm64<bf16, 1, 1><<<mm_grid64(N_NODES, DOUT), 256, 0, stream>>>(
        (const ushort*)g1, HF_LD, (const ushort*)wt_fcg1, HF_LD, fcg1_b, dnb, DOUT,
        N_NODES, HF_LD, DOUT);

    // ---- cross attention + per-graph pool ----
    k_scores_e<<<(N_NODES * 64 + 255) / 256, 256, 0, stream>>>(dnb, kq, qbk, batch,
                                                               enode, sB);
    k_pool_xc<<<B_GRAPH, 384, 0, stream>>>(dnb, vbuf, enode, sB, gstart, pv, xcb);

    // ---- head MLP ----
    mfma_mm64<bf16, 1, 1><<<mm_grid64(B_GRAPH, 1024), 256, 0, stream>>>(
        (const ushort*)xcb, 384, (const ushort*)wt_fc1, 384, fc1_b, h1b, 1024,
        B_GRAPH, 384, 1024);
    mfma_mm64<float, 1, 1><<<mm_grid64(B_GRAPH, 512), 256, 0, stream>>>(
        (const ushort*)h1b, 1024, (const ushort*)wt_fc2, 1024, fc2_b, h2, 512,
        B_GRAPH, 1024, 512);
    k_out<<<(B_GRAPH * 64 + 255) / 256, 256, 0, stream>>>(h2, out_w, out_b, out);
}

// Round 9
// 521.789 us; speedup vs baseline: 1.0760x; 1.0760x over previous
//
#include <hip/hip_runtime.h>
#include <hip/hip_bf16.h>
#include <math.h>

#define N_NODES 40000
#define E_EDGES 160000
#define ETOT    (E_EDGES + N_NODES)   // 200000 (with self-loops)
#define B_GRAPH 1024
#define FXD     78
#define H_HEADS 10
#define HF      (H_HEADS * FXD)       // 780
#define HF_LD   800                   // padded leading dim (16B-aligned rows)
#define XK_LD   96                    // padded K for x (78 -> 96)
#define DOUT    128
#define DP      256
#define SCAN_TILES 40                 // 40 x 1024 >= 40000

typedef __hip_bfloat16 bf16;
typedef __attribute__((ext_vector_type(8))) short short8;
typedef __attribute__((ext_vector_type(4))) float f32x4;

static __device__ __forceinline__ void storev(float* p, float v) { *p = v; }
static __device__ __forceinline__ void storev(bf16* p, float v) { *p = __float2bfloat16(v); }

static __device__ __forceinline__ ushort f2b_bits(float v) {
    bf16 b = __float2bfloat16(v);
    return *reinterpret_cast<ushort*>(&b);
}
static __device__ __forceinline__ float b2f_bits(short u) {
    return __uint_as_float(((unsigned)(unsigned short)u) << 16);
}
static __device__ __forceinline__ int imin(int a, int b) { return a < b ? a : b; }

// R21: conflict-free LDS addressing for 32-ushort (64B) rows.
// data slot s (16B) of row r -> physical slot s ^ ((r>>1)&3).
static __device__ __forceinline__ int lds_off(int row, int slot) {
    return row * 32 + ((slot ^ ((row >> 1) & 3)) << 3);
}

// ---------- transpose tile body (shared tile passed from kernel) ----------
static __device__ void t_tile(const float* __restrict__ w, bf16* __restrict__ wt,
                              int K, int N, int ldk, int ktile, int ntile,
                              float (*tile)[33]) {
    const int kt = ktile * 32, nt = ntile * 32;
    const int tx = threadIdx.x & 31, ty = threadIdx.x >> 5;  // 256 thr: ty 0..7
#pragma unroll
    for (int i = 0; i < 32; i += 8) {
        int k = kt + ty + i, n = nt + tx;
        tile[ty + i][tx] = (k < K && n < N) ? w[(size_t)k * N + n] : 0.f;
    }
    __syncthreads();
#pragma unroll
    for (int i = 0; i < 32; i += 8) {
        int n = nt + ty + i, k = kt + tx;
        if (n < N && k < ldk) wt[(size_t)n * ldk + k] = __float2bfloat16(tile[tx][ty + i]);
    }
}

// ---------- mega-prep: xb convert + 5 transposes + wt_E + cnt/sB zero (R17) ----------
__global__ __launch_bounds__(256)
void k_prep(const float* __restrict__ x, const float* __restrict__ gat_w,
            const float* __restrict__ gcn_w, const float* __restrict__ fcg1_w,
            const float* __restrict__ fc1_w, const float* __restrict__ fc2_w,
            const float* __restrict__ aw_s, const float* __restrict__ aw_d,
            bf16* __restrict__ xb, bf16* __restrict__ wt_gat, bf16* __restrict__ wt_gcn,
            bf16* __restrict__ wt_fcg1, bf16* __restrict__ wt_fc1, bf16* __restrict__ wt_fc2,
            bf16* __restrict__ wt_E, int* __restrict__ cnt, float* __restrict__ sB) {
    __shared__ float tile[32][33];
    int p = blockIdx.x;
    const int NB_XB  = (N_NODES * XK_LD + 255) / 256;   // 15000
    const int TGAT   = 3 * 25;    // (96/32) x ceil(780/32)
    const int TGCN   = 25 * 25;   // (800/32) x 25
    const int TFCG   = 25 * 4;    // (800/32) x (128/32)
    const int TFC1   = 12 * 32;   // (384/32) x (1024/32)
    const int TFC2   = 32 * 16;   // (1024/32) x (512/32)
    const int NB_E   = (20 * XK_LD + 255) / 256;        // 8
    const int NB_CNT = (N_NODES + 255) / 256;           // 157

    if (p < NB_XB) {
        int i = p * 256 + threadIdx.x;
        if (i < N_NODES * XK_LD) {
            int r = i / XK_LD, k = i - r * XK_LD;
            xb[i] = __float2bfloat16((k < FXD) ? x[(size_t)r * FXD + k] : 0.f);
        }
        return;
    }
    p -= NB_XB;
    if (p < TGAT)  { t_tile(gat_w,  wt_gat,  FXD,  HF,   XK_LD, p % 3,  p / 3,  tile); return; }
    p -= TGAT;
    if (p < TGCN)  { t_tile(gcn_w,  wt_gcn,  HF,   HF,   HF_LD, p % 25, p / 25, tile); return; }
    p -= TGCN;
    if (p < TFCG)  { t_tile(fcg1_w, wt_fcg1, HF,   DOUT, HF_LD, p % 25, p / 25, tile); return; }
    p -= TFCG;
    if (p < TFC1)  { t_tile(fc1_w,  wt_fc1,  384,  1024, 384,   p % 12, p / 12, tile); return; }
    p -= TFC1;
    if (p < TFC2)  { t_tile(fc2_w,  wt_fc2,  1024, 512,  1024,  p % 32, p / 32, tile); return; }
    p -= TFC2;
    if (p < NB_E) {
        int idx = p * 256 + threadIdx.x;
        if (idx < 20 * XK_LD) {
            int row = idx / XK_LD, f = idx - row * XK_LD;
            float acc = 0.f;
            if (f < FXD) {
                int h = row % H_HEADS;
                const float* aw = (row < H_HEADS) ? aw_s : aw_d;
                const float* wp = gat_w + (size_t)f * HF + h * FXD;
                const float* ap = aw + h * FXD;
                for (int c = 0; c < FXD; c++) acc += wp[c] * ap[c];
            }
            wt_E[idx] = __float2bfloat16(acc);
        }
        return;
    }
    p -= NB_E;
    if (p < NB_CNT) {
        int i = p * 256 + threadIdx.x;
        if (i < N_NODES) cnt[i] = 0;
        return;
    }
    p -= NB_CNT;
    // sB zero (1024 floats, 4 blocks)
    int i = p * 256 + threadIdx.x;
    if (i < B_GRAPH) sB[i] = 0.f;
}

// ---------- MFMA bf16 GEMM (BM=128, BK=32): swizzled LDS + double buffer (R24) ----------
// One barrier per K-step: write buf[t] -> barrier -> prefetch regs(t+1) -> read buf[t]/MFMA.
// Safety: a wave's reads of buf^1 (iter t-1) are drained by its own lgkmcnt(0) at
// barrier(t) before any wave reaches the writes of buf^1 at iter t+1.
template <typename OutT, int BIAS, int RELU>
__global__ __launch_bounds__(256)
void mfma_mm(const ushort* __restrict__ A, int lda, const ushort* __restrict__ WT, int ldb,
             const float* __restrict__ bias, OutT* __restrict__ C, int ldc,
             int M, int K, int N) {
    const int RT = (M + 127) >> 7;
    const int CT = (N + 127) >> 7;
    const int p = blockIdx.x;
    const int r = (p & 7) + 8 * (p / (8 * CT));
    const int c = (p >> 3) % CT;
    if (r >= RT) return;
    const int m0 = r * 128;
    const int n0 = c * 128;

    __shared__ ushort As[2][128 * 32];
    __shared__ ushort Bs[2][128 * 32];
    const int tid = threadIdx.x;
    const int wave = tid >> 6, lane = tid & 63;
    const int quad = lane >> 4, l16 = lane & 15;
    const int wr = (wave & 1) * 64;   // wave row offset
    const int wc = (wave >> 1) * 64;  // wave col offset

    f32x4 acc[4][4];
#pragma unroll
    for (int mi = 0; mi < 4; mi++)
#pragma unroll
        for (int ni = 0; ni < 4; ni++) acc[mi][ni] = (f32x4){0.f, 0.f, 0.f, 0.f};

    const int ar = tid >> 1;          // staged row 0..127
    const int hh = tid & 1;           // half: data slots 2h, 2h+1
    const int ak = hh * 16;           // ushort offset within row (data layout)
    const int woff0 = lds_off(ar, 2 * hh);
    const int woff1 = lds_off(ar, 2 * hh + 1);

    int grow = m0 + ar; if (grow >= M) grow = M - 1;  // clamp; discarded in epilogue
    int gn   = n0 + ar; if (gn >= N)   gn = N - 1;
    const ushort* arow = A  + (size_t)grow * lda + ak;
    const ushort* brow = WT + (size_t)gn * ldb + ak;

    uint4 a0 = *(const uint4*)(arow);
    uint4 a1 = *(const uint4*)(arow + 8);
    uint4 b0 = *(const uint4*)(brow);
    uint4 b1 = *(const uint4*)(brow + 8);

    int buf = 0;
    for (int kb = 0; kb < K; kb += 32, buf ^= 1) {
        *(uint4*)&As[buf][woff0] = a0;
        *(uint4*)&As[buf][woff1] = a1;
        *(uint4*)&Bs[buf][woff0] = b0;
        *(uint4*)&Bs[buf][woff1] = b1;
        __syncthreads();
        if (kb + 32 < K) {  // prefetch next tile; drained at next barrier / ds_write dep
            a0 = *(const uint4*)(arow + kb + 32);
            a1 = *(const uint4*)(arow + kb + 40);
            b0 = *(const uint4*)(brow + kb + 32);
            b1 = *(const uint4*)(brow + kb + 40);
        }
        short8 af[4], bfr[4];
#pragma unroll
        for (int mi = 0; mi < 4; mi++)
            af[mi] = *(const short8*)&As[buf][lds_off(wr + mi * 16 + l16, quad)];
#pragma unroll
        for (int ni = 0; ni < 4; ni++)
            bfr[ni] = *(const short8*)&Bs[buf][lds_off(wc + ni * 16 + l16, quad)];
#pragma unroll
        for (int mi = 0; mi < 4; mi++)
#pragma unroll
            for (int ni = 0; ni < 4; ni++)
                acc[mi][ni] = __builtin_amdgcn_mfma_f32_16x16x32_bf16(
                    af[mi], bfr[ni], acc[mi][ni], 0, 0, 0);
        // no second barrier: double buffer
    }
#pragma unroll
    for (int mi = 0; mi < 4; mi++)
#pragma unroll
        for (int ni = 0; ni < 4; ni++)
#pragma unroll
            for (int rg = 0; rg < 4; rg++) {
                int row = m0 + wr + mi * 16 + quad * 4 + rg;
                int col = n0 + wc + ni * 16 + l16;
                if (row < M && col < N) {
                    float v = acc[mi][ni][rg];
                    if (BIAS) v += bias[col];
                    if (RELU) v = fmaxf(v, 0.f);
                    storev(&C[(size_t)row * ldc + col], v);
                }
            }
}

static inline int mm_grid(int M, int N) {
    int RT = (M + 127) >> 7, CT = (N + 127) >> 7;
    int RTpad = ((RT + 7) >> 3) << 3;
    return RTpad * CT;
}

// ---------- MFMA bf16 GEMM (BM=64, BK=32): swizzled LDS + double buffer (R24) ----------
template <typename OutT, int BIAS, int RELU>
__global__ __launch_bounds__(256)
void mfma_mm64(const ushort* __restrict__ A, int lda, const ushort* __restrict__ WT, int ldb,
               const float* __restrict__ bias, OutT* __restrict__ C, int ldc,
               int M, int K, int N) {
    const int RT = (M + 63) >> 6;
    const int CT = (N + 127) >> 7;
    const int p = blockIdx.x;
    const int r = (p & 7) + 8 * (p / (8 * CT));
    const int c = (p >> 3) % CT;
    if (r >= RT) return;
    const int m0 = r * 64;
    const int n0 = c * 128;

    __shared__ ushort As[2][64 * 32];
    __shared__ ushort Bs[2][128 * 32];
    const int tid = threadIdx.x;
    const int wave = tid >> 6, lane = tid & 63;
    const int quad = lane >> 4, l16 = lane & 15;
    const int wc = wave * 32;

    f32x4 acc[4][2];
#pragma unroll
    for (int mi = 0; mi < 4; mi++)
#pragma unroll
        for (int ni = 0; ni < 2; ni++) acc[mi][ni] = (f32x4){0.f, 0.f, 0.f, 0.f};

    const int ar  = tid >> 2, asl = tid & 3;          // A: 1 slot/thread
    const int aak = asl * 8;
    const int br  = tid >> 1, bh = tid & 1;           // B: 2 slots/thread
    const int bak = bh * 16;
    const int aoff  = lds_off(ar, asl);
    const int boff0 = lds_off(br, 2 * bh);
    const int boff1 = lds_off(br, 2 * bh + 1);

    int grow = m0 + ar; if (grow >= M) grow = M - 1;
    int gn   = n0 + br; if (gn >= N)   gn = N - 1;
    const ushort* arow = A  + (size_t)grow * lda + aak;
    const ushort* brow = WT + (size_t)gn * ldb + bak;

    uint4 a0 = *(const uint4*)(arow);
    uint4 b0 = *(const uint4*)(brow);
    uint4 b1 = *(const uint4*)(brow + 8);

    int buf = 0;
    for (int kb = 0; kb < K; kb += 32, buf ^= 1) {
        *(uint4*)&As[buf][aoff]  = a0;
        *(uint4*)&Bs[buf][boff0] = b0;
        *(uint4*)&Bs[buf][boff1] = b1;
        __syncthreads();
        if (kb + 32 < K) {
            a0 = *(const uint4*)(arow + kb + 32);
            b0 = *(const uint4*)(brow + kb + 32);
            b1 = *(const uint4*)(brow + kb + 40);
        }
        short8 af[4], bfr[2];
#pragma unroll
        for (int mi = 0; mi < 4; mi++)
            af[mi] = *(const short8*)&As[buf][lds_off(mi * 16 + l16, quad)];
#pragma unroll
        for (int ni = 0; ni < 2; ni++)
            bfr[ni] = *(const short8*)&Bs[buf][lds_off(wc + ni * 16 + l16, quad)];
#pragma unroll
        for (int mi = 0; mi < 4; mi++)
#pragma unroll
            for (int ni = 0; ni < 2; ni++)
                acc[mi][ni] = __builtin_amdgcn_mfma_f32_16x16x32_bf16(
                    af[mi], bfr[ni], acc[mi][ni], 0, 0, 0);
        // no second barrier: double buffer
    }
#pragma unroll
    for (int mi = 0; mi < 4; mi++)
#pragma unroll
        for (int ni = 0; ni < 2; ni++)
#pragma unroll
            for (int rg = 0; rg < 4; rg++) {
                int row = m0 + mi * 16 + quad * 4 + rg;
                int col = n0 + wc + ni * 16 + l16;
                if (row < M && col < N) {
                    float v = acc[mi][ni][rg];
                    if (BIAS) v += bias[col];
                    if (RELU) v = fmaxf(v, 0.f);
                    storev(&C[(size_t)row * ldc + col], v);
                }
            }
}

static inline int mm_grid64(int M, int N) {
    int RT = (M + 63) >> 6, CT = (N + 127) >> 7;
    int RTpad = ((RT + 7) >> 3) << 3;
    return RTpad * CT;
}

// ---------- protein fc ----------
__global__ void k_pv(const float* __restrict__ pvec, const float* __restrict__ w,
                     const float* __restrict__ b, float* __restrict__ pv) {
    __shared__ float sm[DP];
    int bg = blockIdx.x, t = threadIdx.x;
    sm[t] = pvec[(size_t)bg * DP + t];
    __syncthreads();
    float acc = 0.f;
    for (int k = 0; k < DP; k++) acc += sm[k] * w[(size_t)k * DP + t];
    pv[(size_t)bg * DP + t] = fmaxf(acc + b[t], 0.f);
}

// ---------- k/v projections ----------
__global__ void k_kv(const float* __restrict__ pv,
                     const float* __restrict__ kw, const float* __restrict__ kb,
                     const float* __restrict__ vw, const float* __restrict__ vb,
                     float* __restrict__ kbuf, float* __restrict__ vbuf) {
    __shared__ float sm[DP];
    int bg = blockIdx.x, t = threadIdx.x;
    sm[t] = pv[(size_t)bg * DP + t];
    __syncthreads();
    int o = t & 127;
    const float* w = (t < 128) ? kw : vw;
    const float* bb = (t < 128) ? kb : vb;
    float acc = 0.f;
    for (int k = 0; k < DP; k++) acc += sm[k] * w[(size_t)k * 128 + o];
    float v = acc + bb[o];
    if (t < 128) kbuf[(size_t)bg * 128 + o] = v;
    else         vbuf[(size_t)bg * 128 + o] = v;
}

// ---------- kq[b,k] = q_w @ k[b]; qbk[b] = q_b . k[b] (R26: parallel qbk) ----------
__global__ void k_kq(const float* __restrict__ qw, const float* __restrict__ qb,
                     const float* __restrict__ kbuf, float* __restrict__ kq,
                     float* __restrict__ qbk) {
    __shared__ float kb[128];
    __shared__ float wsum[2];
    int b = blockIdx.x, t = threadIdx.x;  // 128 threads
    kb[t] = kbuf[(size_t)b * 128 + t];
    __syncthreads();
    float acc = 0.f;
    for (int o = 0; o < 128; o++) acc += qw[(size_t)t * 128 + o] * kb[o];
    kq[(size_t)b * 128 + t] = acc;
    // parallel qbk: tree-reduce qb . kb over 128 threads (2 waves)
    float pq = qb[t] * kb[t];
    for (int off = 32; off > 0; off >>= 1) pq += __shfl_down(pq, off);
    if ((t & 63) == 0) wsum[t >> 6] = pq;
    __syncthreads();
    if (t == 0) qbk[b] = wsum[0] + wsum[1];
}

// ---------- CSR build: count, hierarchical scan, scatter ----------
__global__ void k_count(const int* __restrict__ ei, int* __restrict__ cnt) {
    int e = blockIdx.x * blockDim.x + threadIdx.x;
    if (e >= ETOT) return;
    int d = (e < E_EDGES) ? ei[E_EDGES + e] : e - E_EDGES;
    atomicAdd(&cnt[d], 1);
}

__global__ void k_scan_tile(const int* __restrict__ cnt, int* __restrict__ tile_sums) {
    __shared__ int sm[256];
    int b = blockIdx.x, t = threadIdx.x;
    int idx = b * 1024 + t * 4;
    int4 v = {0, 0, 0, 0};
    if (idx + 3 < N_NODES) v = *(const int4*)(cnt + idx);
    else {
        v.x = (idx     < N_NODES) ? cnt[idx]     : 0;
        v.y = (idx + 1 < N_NODES) ? cnt[idx + 1] : 0;
        v.z = (idx + 2 < N_NODES) ? cnt[idx + 2] : 0;
        v.w = (idx + 3 < N_NODES) ? cnt[idx + 3] : 0;
    }
    sm[t] = v.x + v.y + v.z + v.w;
    __syncthreads();
    for (int off = 128; off > 0; off >>= 1) {
        if (t < off) sm[t] += sm[t + off];
        __syncthreads();
    }
    if (t == 0) tile_sums[b] = sm[0];
}

__global__ void k_scan_top(const int* __restrict__ tile_sums, int* __restrict__ tile_off,
                           int* __restrict__ rowptr) {
    if (threadIdx.x == 0) {
        int run = 0;
        for (int i = 0; i < SCAN_TILES; i++) { tile_off[i] = run; run += tile_sums[i]; }
        rowptr[N_NODES] = run;
    }
}

// R17: also emits dinv (from cnt) and gstart (from batch) -- 2 fewer launches.
__global__ void k_scan_write(const int* __restrict__ cnt, const int* __restrict__ tile_off,
                             const int* __restrict__ batch,
                             int* __restrict__ rowptr, int* __restrict__ cursor,
                             float* __restrict__ dinv, int* __restrict__ gstart) {
    __shared__ int sm[256];
    int b = blockIdx.x, t = threadIdx.x;
    int idx = b * 1024 + t * 4;
    int4 v = {0, 0, 0, 0};
    if (idx + 3 < N_NODES) v = *(const int4*)(cnt + idx);
    else {
        v.x = (idx     < N_NODES) ? cnt[idx]     : 0;
        v.y = (idx + 1 < N_NODES) ? cnt[idx + 1] : 0;
        v.z = (idx + 2 < N_NODES) ? cnt[idx + 2] : 0;
        v.w = (idx + 3 < N_NODES) ? cnt[idx + 3] : 0;
    }
    int tsum = v.x + v.y + v.z + v.w;
    sm[t] = tsum;
    __syncthreads();
    for (int off = 1; off < 256; off <<= 1) {
        int add = (t >= off) ? sm[t - off] : 0;
        __syncthreads();
        sm[t] += add;
        __syncthreads();
    }
    int toff = tile_off[b] + sm[t] - tsum;  // exclusive thread offset
    int e0 = toff, e1 = e0 + v.x, e2 = e1 + v.y, e3 = e2 + v.z;
    if (idx     < N_NODES) { rowptr[idx]     = e0; cursor[idx]     = e0; }
    if (idx + 1 < N_NODES) { rowptr[idx + 1] = e1; cursor[idx + 1] = e1; }
    if (idx + 2 < N_NODES) { rowptr[idx + 2] = e2; cursor[idx + 2] = e2; }
    if (idx + 3 < N_NODES) { rowptr[idx + 3] = e3; cursor[idx + 3] = e3; }
    int cc[4] = {v.x, v.y, v.z, v.w};
#pragma unroll
    for (int j = 0; j < 4; j++) {
        int n = idx + j;
        if (n >= N_NODES) break;
        dinv[n] = (cc[j] > 0) ? 1.0f / sqrtf((float)cc[j]) : 0.f;
        int bg = batch[n];
        int bp = (n == 0) ? -1 : batch[n - 1];
        for (int g = bp + 1; g <= bg; g++) gstart[g] = n;
        if (n == N_NODES - 1)
            for (int g = bg + 1; g <= B_GRAPH; g++) gstart[g] = N_NODES;
    }
}

// scatter resolves src directly: aggregation chain loses the ei[e] hop (R13).
__global__ void k_scatter(const int* __restrict__ ei, int* __restrict__ cursor,
                          int* __restrict__ slist) {
    int e = blockIdx.x * blockDim.x + threadIdx.x;
    if (e >= ETOT) return;
    int s, d;
    if (e < E_EDGES) { s = ei[e]; d = ei[E_EDGES + e]; }
    else             { s = d = e - E_EDGES; }
    int pos = atomicAdd(&cursor[d], 1);
    slist[pos] = s;
}

// ---------- fused GAT softmax + aggregation: wave-per-dst, depth-2 ring (R20) ----------
__global__ __launch_bounds__(256)
void k_gat_fused(const int* __restrict__ rowptr, const int* __restrict__ slist,
                 const bf16* __restrict__ h, const float* __restrict__ aa,
                 const float* __restrict__ bias, bf16* __restrict__ outb) {
    const int tid = threadIdx.x;
    const int w = tid >> 6, lane = tid & 63;
    const int d = blockIdx.x * 4 + w;
    const int beg = rowptr[d], end = rowptr[d + 1];

    const float adst_l = (lane < H_HEADS) ? aa[(size_t)d * 20 + 10 + lane] : 0.f;

    const int cA = lane * 8;
    const int cB = (lane + 64) * 8;
    const bool hasB = cB < HF_LD;  // lane < 36
    int hloA = cA / FXD;       if (hloA > 9) hloA = 9;
    int hhiA = (cA + 7) / FXD; if (hhiA > 9) hhiA = 9;
    int hloB = cB / FXD;       if (hloB > 9) hloB = 9;
    int hhiB = (cB + 7) / FXD; if (hhiB > 9) hhiB = 9;
    bool selA[8], selB[8];
#pragma unroll
    for (int j = 0; j < 8; j++) {
        int ha = (cA + j) / FXD; if (ha > 9) ha = 9;
        int hb = (cB + j) / FXD; if (hb > 9) hb = 9;
        selA[j] = (ha != hloA);
        selB[j] = (hb != hloB);
    }
    float accA[8], accB[8];
#pragma unroll
    for (int j = 0; j < 8; j++) { accA[j] = 0.f; accB[j] = 0.f; }
    float s_l = 0.f;

    const ushort* hb16 = (const ushort*)h;
    const int e1 = end - 1;   // deg >= 1 guaranteed (self-loop)

    auto edge = [&](float ae, const short8& va, const short8& vb) {
        float ex = 0.f;
        if (lane < H_HEADS) {
            float a = ae + adst_l;
            a = (a >= 0.f) ? a : 0.2f * a;
            ex = __expf(a);
            s_l += ex;
        }
        float exloA = __shfl(ex, hloA), exhiA = __shfl(ex, hhiA);
#pragma unroll
        for (int j = 0; j < 8; j++)
            accA[j] += (selA[j] ? exhiA : exloA) * b2f_bits(va[j]);
        if (hasB) {
            float exloB = __shfl(ex, hloB), exhiB = __shfl(ex, hhiB);
#pragma unroll
            for (int j = 0; j < 8; j++)
                accB[j] += (selB[j] ? exhiB : exloB) * b2f_bits(vb[j]);
        }
    };

    // ring state: rows of edges i,i+1 resident; src indices of i+2,i+3 resident
    int s0 = slist[beg];
    int s1 = slist[imin(beg + 1, e1)];
    int s2 = slist[imin(beg + 2, e1)];
    int s3 = slist[imin(beg + 3, e1)];
    short8 va0, va1, vb0 = {0,0,0,0,0,0,0,0}, vb1 = {0,0,0,0,0,0,0,0};
    float a0 = 0.f, a1 = 0.f;
    {
        const ushort* hr0 = hb16 + (size_t)s0 * HF_LD;
        const ushort* hr1 = hb16 + (size_t)s1 * HF_LD;
        va0 = *(const short8*)(hr0 + cA);
        va1 = *(const short8*)(hr1 + cA);
        if (hasB) { vb0 = *(const short8*)(hr0 + cB); vb1 = *(const short8*)(hr1 + cB); }
        if (lane < H_HEADS) {
            a0 = aa[(size_t)s0 * 20 + lane];
            a1 = aa[(size_t)s1 * 20 + lane];
        }
    }
    int i = beg;
    for (; i + 1 < end; i += 2) {
        // row loads for edges i+2,i+3: addresses already resident, issue immediately
        const ushort* hr2 = hb16 + (size_t)s2 * HF_LD;
        const ushort* hr3 = hb16 + (size_t)s3 * HF_LD;
        short8 nva0 = *(const short8*)(hr2 + cA);
        short8 nva1 = *(const short8*)(hr3 + cA);
        short8 nvb0 = vb0, nvb1 = vb1;
        if (hasB) { nvb0 = *(const short8*)(hr2 + cB); nvb1 = *(const short8*)(hr3 + cB); }
        float na0 = 0.f, na1 = 0.f;
        if (lane < H_HEADS) {
            na0 = aa[(size_t)s2 * 20 + lane];
            na1 = aa[(size_t)s3 * 20 + lane];
        }
        // index prefetch for i+4,i+5 (independent loads)
        int ns2 = slist[imin(i + 4, e1)];
        int ns3 = slist[imin(i + 5, e1)];
        // compute edges i, i+1 (order preserved)
        edge(a0, va0, vb0);
        edge(a1, va1, vb1);
        va0 = nva0; vb0 = nvb0; a0 = na0;
        va1 = nva1; vb1 = nvb1; a1 = na1;
        s2 = ns2; s3 = ns3;
    }
    if (i < end) edge(a0, va0, vb0);

    float sinv_l = 1.f / (s_l + 1e-16f);  // valid for lanes<10

    ushort* orow = (ushort*)outb + (size_t)d * HF_LD;
    {
        float silo = __shfl(sinv_l, hloA), sihi = __shfl(sinv_l, hhiA);
        union { ushort u[8]; uint4 q; } pk;
#pragma unroll
        for (int j = 0; j < 8; j++) {
            float bz = (cA + j < HF) ? bias[cA + j] : 0.f;
            pk.u[j] = f2b_bits(fmaxf(accA[j] * (selA[j] ? sihi : silo) + bz, 0.f));
        }
        *(uint4*)(orow + cA) = pk.q;
    }
    if (hasB) {
        float silo = __shfl(sinv_l, hloB), sihi = __shfl(sinv_l, hhiB);
        union { ushort u[8]; uint4 q; } pk;
#pragma unroll
        for (int j = 0; j < 8; j++) {
            float bz = (cB + j < HF) ? bias[cB + j] : 0.f;
            pk.u[j] = f2b_bits(fmaxf(accB[j] * (selB[j] ? sihi : silo) + bz, 0.f));
        }
        *(uint4*)(orow + cB) = pk.q;
    }
}

// ---------- GCN aggregation: wave-per-dst, depth-2 ring (R20) ----------
__global__ __launch_bounds__(256)
void k_gcn_aggr_v(const int* __restrict__ rowptr, const int* __restrict__ slist,
                  const bf16* __restrict__ hg,
                  const float* __restrict__ dinv, const float* __restrict__ bias,
                  bf16* __restrict__ outb) {
    const int tid = threadIdx.x;
    const int w = tid >> 6, lane = tid & 63;
    const int d = blockIdx.x * 4 + w;
    const float dv = dinv[d];
    const int cA = lane * 8;
    const int cB = (lane + 64) * 8;
    const bool hasB = cB < HF_LD;
    float accA[8], accB[8];
#pragma unroll
    for (int j = 0; j < 8; j++) { accA[j] = 0.f; accB[j] = 0.f; }
    const int beg = rowptr[d], end = rowptr[d + 1];
    const ushort* hb16 = (const ushort*)hg;
    const int e1 = end - 1;

    auto edge = [&](float we, const short8& va, const short8& vb) {
#pragma unroll
        for (int j = 0; j < 8; j++) accA[j] += we * b2f_bits(va[j]);
        if (hasB) {
#pragma unroll
            for (int j = 0; j < 8; j++) accB[j] += we * b2f_bits(vb[j]);
        }
    };

    int s0 = slist[beg];
    int s1 = slist[imin(beg + 1, e1)];
    int s2 = slist[imin(beg + 2, e1)];
    int s3 = slist[imin(beg + 3, e1)];
    short8 va0, va1, vb0 = {0,0,0,0,0,0,0,0}, vb1 = {0,0,0,0,0,0,0,0};
    float w0, w1;
    {
        const ushort* hr0 = hb16 + (size_t)s0 * HF_LD;
        const ushort* hr1 = hb16 + (size_t)s1 * HF_LD;
        va0 = *(const short8*)(hr0 + cA);
        va1 = *(const short8*)(hr1 + cA);
        if (hasB) { vb0 = *(const short8*)(hr0 + cB); vb1 = *(const short8*)(hr1 + cB); }
        w0 = dinv[s0] * dv;
        w1 = dinv[s1] * dv;
    }
    int i = beg;
    for (; i + 1 < end; i += 2) {
        const ushort* hr2 = hb16 + (size_t)s2 * HF_LD;
        const ushort* hr3 = hb16 + (size_t)s3 * HF_LD;
        short8 nva0 = *(const short8*)(hr2 + cA);
        short8 nva1 = *(const short8*)(hr3 + cA);
        short8 nvb0 = vb0, nvb1 = vb1;
        if (hasB) { nvb0 = *(const short8*)(hr2 + cB); nvb1 = *(const short8*)(hr3 + cB); }
        float nw0 = dinv[s2] * dv;
        float nw1 = dinv[s3] * dv;
        int ns2 = slist[imin(i + 4, e1)];
        int ns3 = slist[imin(i + 5, e1)];
        edge(w0, va0, vb0);
        edge(w1, va1, vb1);
        va0 = nva0; vb0 = nvb0; w0 = nw0;
        va1 = nva1; vb1 = nvb1; w1 = nw1;
        s2 = ns2; s3 = ns3;
    }
    if (i < end) edge(w0, va0, vb0);

    ushort* orow = (ushort*)outb + (size_t)d * HF_LD;
    {
        union { ushort u[8]; uint4 q; } pk;
#pragma unroll
        for (int j = 0; j < 8; j++) {
            float bz = (cA + j < HF) ? bias[cA + j] : 0.f;
            pk.u[j] = f2b_bits(fmaxf(accA[j] + bz, 0.f));
        }
        *(uint4*)(orow + cA) = pk.q;
    }
    if (hasB) {
        union { ushort u[8]; uint4 q; } pk;
#pragma unroll
        for (int j = 0; j < 8; j++) {
            float bz = (cB + j < HF) ? bias[cB + j] : 0.f;
            pk.u[j] = f2b_bits(fmaxf(accB[j] + bz, 0.f));
        }
        *(uint4*)(orow + cB) = pk.q;
    }
}

// ---------- cross-attention: exp(score) + segment sum (dn in bf16, R17) ----------
__global__ void k_scores_e(const bf16* __restrict__ dnb, const float* __restrict__ kq,
                           const float* __restrict__ qbk, const int* __restrict__ batch,
                           float* __restrict__ enode, float* __restrict__ sB) {
    int wv = (blockIdx.x * blockDim.x + threadIdx.x) >> 6;
    int lane = threadIdx.x & 63;
    if (wv >= N_NODES) return;
    int b = batch[wv];
    const ushort* dp = (const ushort*)dnb + (size_t)wv * DOUT;
    const float* kp = kq + (size_t)b * DOUT;
    uint dd = *(const uint*)(dp + lane * 2);
    float p = b2f_bits((ushort)dd) * kp[lane * 2]
            + b2f_bits((ushort)(dd >> 16)) * kp[lane * 2 + 1];
    for (int off = 32; off > 0; off >>= 1) p += __shfl_down(p, off);
    if (lane == 0) {
        float ex = __expf((p + qbk[b]) * 0.08838834764831845f);  // 1/sqrt(128)
        enode[wv] = ex;
        atomicAdd(&sB[b], ex);
    }
}

// ---------- per-graph pool + concat -> xcb (dn in bf16, uint loads, R17) ----------
__global__ __launch_bounds__(384)
void k_pool_xc(const bf16* __restrict__ dnb, const float* __restrict__ vbuf,
               const float* __restrict__ enode, const float* __restrict__ sB,
               const int* __restrict__ gstart, const float* __restrict__ pv,
               bf16* __restrict__ xcb) {
    int g = blockIdx.x, t = threadIdx.x;
    if (t < 64) {
        int s0 = gstart[g], s1 = gstart[g + 1];
        float inv = 1.f / sB[g];  // unused if empty
        float vb0 = vbuf[(size_t)g * 128 + 2 * t];
        float vb1 = vbuf[(size_t)g * 128 + 2 * t + 1];
        float m0 = -3.4e38f, m1 = -3.4e38f;
        const ushort* dp = (const ushort*)dnb;
        for (int n = s0; n < s1; n++) {
            uint dd = *(const uint*)(dp + (size_t)n * 128 + 2 * t);
            float a = enode[n] * inv;
            m0 = fmaxf(m0, b2f_bits((ushort)dd) + a * vb0);
            m1 = fmaxf(m1, b2f_bits((ushort)(dd >> 16)) + a * vb1);
        }
        bool ne = s1 > s0;
        xcb[(size_t)g * 384 + 2 * t]     = __float2bfloat16(ne ? m0 : 0.f);
        xcb[(size_t)g * 384 + 2 * t + 1] = __float2bfloat16(ne ? m1 : 0.f);
    } else if (t >= 128) {
        xcb[(size_t)g * 384 + t] = __float2bfloat16(pv[(size_t)g * DP + (t - 128)]);
    }
}

// ---------- final head ----------
__global__ void k_out(const float* __restrict__ h2, const float* __restrict__ ow,
                      const float* __restrict__ ob, float* __restrict__ out) {
    int row = (blockIdx.x * blockDim.x + threadIdx.x) >> 6;
    int lane = threadIdx.x & 63;
    if (row >= B_GRAPH) return;
    float p = 0.f;
    for (int j = lane; j < 512; j += 64) p += h2[(size_t)row * 512 + j] * ow[j];
    for (int off = 32; off > 0; off >>= 1) p += __shfl_down(p, off);
    if (lane == 0) out[row] = p + ob[0];
}

// ---------- workspace-overflow sentinel ----------
__global__ void k_fail(float* __restrict__ out, int n) {
    int i = blockIdx.x * blockDim.x + threadIdx.x;
    if (i < n) out[i] = 12345.0f;
}

extern "C" void kernel_launch(void* const* d_in, const int* in_sizes, int n_in,
                              void* d_out, int out_size, void* d_ws, size_t ws_size,
                              hipStream_t stream) {
    const float* x        = (const float*)d_in[0];
    const int*   ei       = (const int*)d_in[1];
    const int*   batch    = (const int*)d_in[2];
    const float* pvec     = (const float*)d_in[3];
    const float* pfc_w    = (const float*)d_in[4];
    const float* pfc_b    = (const float*)d_in[5];
    const float* gat_w    = (const float*)d_in[6];
    const float* gat_asrc = (const float*)d_in[7];
    const float* gat_adst = (const float*)d_in[8];
    const float* gat_b    = (const float*)d_in[9];
    const float* gcn_w    = (const float*)d_in[10];
    const float* gcn_b    = (const float*)d_in[11];
    const float* fcg1_w   = (const float*)d_in[12];
    const float* fcg1_b   = (const float*)d_in[13];
    const float* q_w      = (const float*)d_in[14];
    const float* q_b      = (const float*)d_in[15];
    const float* k_w      = (const float*)d_in[16];
    const float* k_b      = (const float*)d_in[17];
    const float* v_w      = (const float*)d_in[18];
    const float* v_b      = (const float*)d_in[19];
    const float* fc1_w    = (const float*)d_in[20];
    const float* fc1_b    = (const float*)d_in[21];
    const float* fc2_w    = (const float*)d_in[22];
    const float* fc2_b    = (const float*)d_in[23];
    const float* out_w    = (const float*)d_in[24];
    const float* out_b    = (const float*)d_in[25];
    float* out = (float*)d_out;

    // ---- workspace layout (bytes, 256-aligned) ----
    char* base = (char*)d_ws;
    size_t off = 0;
    auto alloc = [&](size_t bytes) -> void* {
        void* r = base + off;
        off += (bytes + 255) & ~(size_t)255;
        return r;
    };
    float*    pv      = (float*)alloc((size_t)B_GRAPH * DP * 4);
    bf16*     xb      = (bf16*)alloc((size_t)N_NODES * XK_LD * 2);
    bf16*     wt_gat  = (bf16*)alloc((size_t)HF * XK_LD * 2);
    bf16*     wt_gcn  = (bf16*)alloc((size_t)HF * HF_LD * 2);
    bf16*     wt_fcg1 = (bf16*)alloc((size_t)DOUT * HF_LD * 2);
    bf16*     wt_fc1  = (bf16*)alloc((size_t)1024 * 384 * 2);
    bf16*     wt_fc2  = (bf16*)alloc((size_t)512 * 1024 * 2);
    bf16*     wt_E    = (bf16*)alloc((size_t)20 * XK_LD * 2);
    bf16*     hB      = (bf16*)alloc((size_t)N_NODES * HF_LD * 2);  // h, then hg (ld 800)
    bf16*     g1      = (bf16*)alloc((size_t)N_NODES * HF_LD * 2);  // aggr outs (ld 800)
    float*    aa      = (float*)alloc((size_t)N_NODES * 20 * 4);    // [n][20] logits
    int*      cnt     = (int*)alloc((size_t)N_NODES * 4);
    int*      rowptr  = (int*)alloc((size_t)(N_NODES + 1) * 4);
    int*      cursor  = (int*)alloc((size_t)N_NODES * 4);
    int*      slist   = (int*)alloc((size_t)ETOT * 4);
    int*      tsums   = (int*)alloc((size_t)SCAN_TILES * 4);
    int*      toff    = (int*)alloc((size_t)SCAN_TILES * 4);
    int*      gstart  = (int*)alloc((size_t)(B_GRAPH + 1) * 4);
    float*    dinv    = (float*)alloc((size_t)N_NODES * 4);
    bf16*     dnb     = (bf16*)alloc((size_t)N_NODES * DOUT * 2);
    float*    kbuf    = (float*)alloc((size_t)B_GRAPH * 128 * 4);
    float*    vbuf    = (float*)alloc((size_t)B_GRAPH * 128 * 4);
    float*    kq      = (float*)alloc((size_t)B_GRAPH * 128 * 4);
    float*    qbk     = (float*)alloc((size_t)B_GRAPH * 4);
    float*    enode   = (float*)alloc((size_t)N_NODES * 4);
    float*    sB      = (float*)alloc((size_t)B_GRAPH * 4);
    bf16*     xcb     = (bf16*)alloc((size_t)B_GRAPH * 384 * 2);
    bf16*     h1b     = (bf16*)alloc((size_t)B_GRAPH * 1024 * 2);
    float*    h2      = (float*)alloc((size_t)B_GRAPH * 512 * 4);

    if (off > ws_size) {
        k_fail<<<(out_size + 255) / 256, 256, 0, stream>>>(out, out_size);
        return;
    }

    // ---- mega-prep (converts + transposes + wt_E + cnt/sB zero) ----
    {
        int nb = (N_NODES * XK_LD + 255) / 256   // xb
               + 3 * 25 + 25 * 25 + 25 * 4 + 12 * 32 + 32 * 16  // transposes
               + (20 * XK_LD + 255) / 256        // wt_E
               + (N_NODES + 255) / 256           // cnt zero
               + (B_GRAPH + 255) / 256;          // sB zero
        k_prep<<<nb, 256, 0, stream>>>(x, gat_w, gcn_w, fcg1_w, fc1_w, fc2_w,
                                       gat_asrc, gat_adst,
                                       xb, wt_gat, wt_gcn, wt_fcg1, wt_fc1, wt_fc2,
                                       wt_E, cnt, sB);
    }

    // ---- protein path ----
    k_pv<<<B_GRAPH, 256, 0, stream>>>(pvec, pfc_w, pfc_b, pv);
    k_kv<<<B_GRAPH, 256, 0, stream>>>(pv, k_w, k_b, v_w, v_b, kbuf, vbuf);
    k_kq<<<B_GRAPH, 128, 0, stream>>>(q_w, q_b, kbuf, kq, qbk);

    // ---- CSR build + dinv + graph ranges ----
    k_count<<<(ETOT + 255) / 256, 256, 0, stream>>>(ei, cnt);
    k_scan_tile<<<SCAN_TILES, 256, 0, stream>>>(cnt, tsums);
    k_scan_top<<<1, 64, 0, stream>>>(tsums, toff, rowptr);
    k_scan_write<<<SCAN_TILES, 256, 0, stream>>>(cnt, toff, batch, rowptr, cursor,
                                                 dinv, gstart);
    k_scatter<<<(ETOT + 255) / 256, 256, 0, stream>>>(ei, cursor, slist);

    // ---- GAT: logits GEMM + feature GEMM + fused aggr ----
    mfma_mm64<float, 0, 0><<<mm_grid64(N_NODES, 20), 256, 0, stream>>>(
        (const ushort*)xb, XK_LD, (const ushort*)wt_E, XK_LD, nullptr, aa, 20,
        N_NODES, XK_LD, 20);
    mfma_mm<bf16, 0, 0><<<mm_grid(N_NODES, HF), 256, 0, stream>>>(
        (const ushort*)xb, XK_LD, (const ushort*)wt_gat, XK_LD, nullptr, hB, HF_LD,
        N_NODES, XK_LD, HF);
    k_gat_fused<<<N_NODES / 4, 256, 0, stream>>>(rowptr, slist, hB, aa, gat_b, g1);

    // ---- GCN (dbuf GEMM, R24) ----
    mfma_mm<bf16, 0, 0><<<mm_grid(N_NODES, HF), 256, 0, stream>>>(
        (const ushort*)g1, HF_LD, (const ushort*)wt_gcn, HF_LD, nullptr, hB, HF_LD,
        N_NODES, HF_LD, HF);
    k_gcn_aggr_v<<<N_NODES / 4, 256, 0, stream>>>(rowptr, slist, hB, dinv, gcn_b, g1);

    // ---- fc_g1 (bf16 out) ----
    mfma_mm64<bf16, 1, 1><<<mm_grid64(N_NODES, DOUT), 256, 0, stream>>>(
        (const ushort*)g1, HF_LD, (const ushort*)wt_fcg1, HF_LD, fcg1_b, dnb, DOUT,
        N_NODES, HF_LD, DOUT);

    // ---- cross attention + per-graph pool ----
    k_scores_e<<<(N_NODES * 64 + 255) / 256, 256, 0, stream>>>(dnb, kq, qbk, batch,
                                                               enode, sB);
    k_pool_xc<<<B_GRAPH, 384, 0, stream>>>(dnb, vbuf, enode, sB, gstart, pv, xcb);

    // ---- head MLP ----
    mfma_mm64<bf16, 1, 1><<<mm_grid64(B_GRAPH, 1024), 256, 0, stream>>>(
        (const ushort*)xcb, 384, (const ushort*)wt_fc1, 384, fc1_b, h1b, 1024,
        B_GRAPH, 384, 1024);
    mfma_mm64<float, 1, 1><<<mm_grid64(B_GRAPH, 512), 256, 0, stream>>>(
        (const ushort*)h1b, 1024, (const ushort*)wt_fc2, 1024, fc2_b, h2, 512,
        B_GRAPH, 1024, 512);
    k_out<<<(B_GRAPH * 64 + 255) / 256, 256, 0, stream>>>(h2, out_w, out_b, out);
}